// Round 6
// baseline (358.399 us; speedup 1.0000x reference)
//
#include <hip/hip_runtime.h>

#define BB 4
#define SS 2048
#define DD 768
#define HH 12
#define DKK 64
#define MM (BB*SS)   // 8192

typedef __attribute__((ext_vector_type(8))) short bf16x8;
typedef __attribute__((ext_vector_type(4))) float f32x4;

// async 16B global->LDS (m97-verified width)
#define GLDS(g, l) __builtin_amdgcn_global_load_lds( \
    (const __attribute__((address_space(1))) unsigned int*)(g), \
    (__attribute__((address_space(3))) unsigned int*)(l), 16, 0, 0)

__device__ __forceinline__ unsigned short f2bf(float f) {
    union { float f; unsigned int u; } v; v.f = f;
    unsigned int r = v.u + 0x7fffu + ((v.u >> 16) & 1u);   // RNE
    return (unsigned short)(r >> 16);
}

#define EXPSCALE 0.18033688011112042f   // log2(e) / sqrt(DK)

// ---------------- fused prep: 7x fp32->bf16 cvt + mask bit-pack, one launch ----------------
#define NACT4 (MM*DD/4)
#define ABLK  (NACT4/256)      // 6144
#define NW4   (DD*DD/4)
#define WBLK  (NW4/256)        // 576
#define MBLK  (BB*SS*SS/256)   // 65536

__global__ void prep(
    const float* __restrict__ Q, const float* __restrict__ K, const float* __restrict__ V,
    const float* __restrict__ Wq, const float* __restrict__ Wk, const float* __restrict__ Wv,
    const float* __restrict__ Wo, const int* __restrict__ mask,
    unsigned short* __restrict__ Qc, unsigned short* __restrict__ Kc, unsigned short* __restrict__ Vc,
    unsigned short* __restrict__ Wqc, unsigned short* __restrict__ Wkc, unsigned short* __restrict__ Wvc,
    unsigned short* __restrict__ Woc, unsigned int* __restrict__ mbits)
{
    const int bx = blockIdx.x;
    if (bx < 3 * ABLK) {
        const int seg = bx / ABLK;
        const float* s = seg == 0 ? Q : seg == 1 ? K : V;
        unsigned short* d = seg == 0 ? Qc : seg == 1 ? Kc : Vc;
        const int i = (bx - seg * ABLK) * 256 + threadIdx.x;
        float4 v = ((const float4*)s)[i];
        ushort4 o;
        o.x = f2bf(v.x); o.y = f2bf(v.y); o.z = f2bf(v.z); o.w = f2bf(v.w);
        ((ushort4*)d)[i] = o;
    } else if (bx < 3 * ABLK + 4 * WBLK) {
        const int b2 = bx - 3 * ABLK;
        const int seg = b2 / WBLK;
        const float* s = seg == 0 ? Wq : seg == 1 ? Wk : seg == 2 ? Wv : Wo;
        unsigned short* d = seg == 0 ? Wqc : seg == 1 ? Wkc : seg == 2 ? Wvc : Woc;
        const int i = (b2 - seg * WBLK) * 256 + threadIdx.x;
        float4 v = ((const float4*)s)[i];
        ushort4 o;
        o.x = f2bf(v.x); o.y = f2bf(v.y); o.z = f2bf(v.z); o.w = f2bf(v.w);
        ((ushort4*)d)[i] = o;
    } else {
        const int t = (bx - (3 * ABLK + 4 * WBLK)) * 256 + threadIdx.x;
        const int m = mask[t];
        unsigned long long b = __ballot(m != 0);
        const int l = t & 63;
        if (l == 0)       mbits[t >> 5] = (unsigned int)b;
        else if (l == 32) mbits[t >> 5] = (unsigned int)(b >> 32);
    }
}

// ---------------- QKV projection GEMM: y = X @ W^T + b (NT, bf16 MFMA) ----------------
// BK=64, XOR-swizzled LDS. For q/k the MFMA operands are SWAPPED (mfma(b,a)): C-layout
// becomes col=token, reg=4 consecutive features -> vectorized ushort4 epilogue stores
// (16 instead of 64 scalar) + float4 bias loads. V stays unswapped (reg=token) for the
// [dk][s] transpose store. mat 0 pre-scales Q by EXPSCALE.
__global__ __launch_bounds__(256) void gemm_qkv(
    const unsigned short* __restrict__ Qc, const unsigned short* __restrict__ Kc, const unsigned short* __restrict__ Vc,
    const unsigned short* __restrict__ Wq, const unsigned short* __restrict__ Wk, const unsigned short* __restrict__ Wv,
    const float* __restrict__ bq, const float* __restrict__ bk, const float* __restrict__ bv,
    unsigned short* __restrict__ qb, unsigned short* __restrict__ kb, unsigned short* __restrict__ vt)
{
    __shared__ unsigned short As[128*64];
    __shared__ unsigned short Bs[128*64];
    const int mat = blockIdx.z;
    const unsigned short* X = mat == 0 ? Qc : mat == 1 ? Kc : Vc;
    const unsigned short* W = mat == 0 ? Wq : mat == 1 ? Wk : Wv;
    const float* bias        = mat == 0 ? bq : mat == 1 ? bk : bv;

    const int tid  = threadIdx.x;
    const int lane = tid & 63;
    const int w    = tid >> 6;
    const int wm   = w >> 1, wn = w & 1;
    const int quad = lane >> 4, c = lane & 15;
    const int m0 = blockIdx.y * 128, n0 = blockIdx.x * 128;

    f32x4 acc[4][4];   // q/k (swapped): acc[tn][tm]; v: acc[tm][tn]
    #pragma unroll
    for (int i = 0; i < 4; i++)
        #pragma unroll
        for (int j = 0; j < 4; j++) acc[i][j] = (f32x4){0.f, 0.f, 0.f, 0.f};

    const unsigned short* Xg[4]; const unsigned short* Wg[4]; int dst[4];
    #pragma unroll
    for (int j = 0; j < 4; j++) {
        const int ch = tid + j * 256;
        const int row = ch >> 3, sl = ch & 7;
        const int lc = (sl ^ (row & 7)) << 3;
        Xg[j] = X + (size_t)(m0 + row) * DD + lc;
        Wg[j] = W + (size_t)(n0 + row) * DD + lc;
        dst[j] = ch * 8;
    }
    const int cswz = c & 7;

    for (int k0 = 0; k0 < DD; k0 += 64) {
        #pragma unroll
        for (int j = 0; j < 4; j++) {
            GLDS(Xg[j] + k0, As + dst[j]);
            GLDS(Wg[j] + k0, Bs + dst[j]);
        }
        __syncthreads();
        #pragma unroll
        for (int kk = 0; kk < 2; kk++) {
            bf16x8 a[4], b[4];
            #pragma unroll
            for (int t = 0; t < 4; t++) {
                const int ra = wm * 64 + t * 16 + c;
                const int rb = wn * 64 + t * 16 + c;
                a[t] = *(const bf16x8*)(As + ra * 64 + (((kk * 4 + quad) ^ cswz) << 3));
                b[t] = *(const bf16x8*)(Bs + rb * 64 + (((kk * 4 + quad) ^ cswz) << 3));
            }
            if (mat < 2) {
                #pragma unroll
                for (int tn = 0; tn < 4; tn++)
                    #pragma unroll
                    for (int tm = 0; tm < 4; tm++)
                        acc[tn][tm] = __builtin_amdgcn_mfma_f32_16x16x32_bf16(b[tn], a[tm], acc[tn][tm], 0, 0, 0);
            } else {
                #pragma unroll
                for (int tm = 0; tm < 4; tm++)
                    #pragma unroll
                    for (int tn = 0; tn < 4; tn++)
                        acc[tm][tn] = __builtin_amdgcn_mfma_f32_16x16x32_bf16(a[tm], b[tn], acc[tm][tn], 0, 0, 0);
            }
        }
        __syncthreads();
    }

    if (mat < 2) {
        // swapped C-layout: col=c=token, reg r = feature (consecutive) -> ushort4 stores
        unsigned short* out = mat == 0 ? qb : kb;
        const float scale = mat == 0 ? EXPSCALE : 1.0f;
        #pragma unroll
        for (int tn = 0; tn < 4; tn++) {
            const int featbase = n0 + wn * 64 + tn * 16 + quad * 4;
            const float4 bz = *(const float4*)(bias + featbase);
            #pragma unroll
            for (int tm = 0; tm < 4; tm++) {
                const int token = m0 + wm * 64 + tm * 16 + c;
                ushort4 pk;
                pk.x = f2bf((acc[tn][tm][0] + bz.x) * scale);
                pk.y = f2bf((acc[tn][tm][1] + bz.y) * scale);
                pk.z = f2bf((acc[tn][tm][2] + bz.z) * scale);
                pk.w = f2bf((acc[tn][tm][3] + bz.w) * scale);
                *(ushort4*)(out + (size_t)token * DD + featbase) = pk;
            }
        }
    } else {
        #pragma unroll
        for (int tn = 0; tn < 4; tn++) {
            const int col = n0 + wn * 64 + tn * 16 + c;
            const float bz = bias[col];
            const int h = col >> 6, dk = col & 63;
            #pragma unroll
            for (int tm = 0; tm < 4; tm++) {
                const int row = m0 + wm * 64 + tm * 16 + quad * 4;
                const int bb = row >> 11, s = row & 2047;
                ushort4 pk;
                pk.x = f2bf(acc[tm][tn][0] + bz);
                pk.y = f2bf(acc[tm][tn][1] + bz);
                pk.z = f2bf(acc[tm][tn][2] + bz);
                pk.w = f2bf(acc[tm][tn][3] + bz);
                *(ushort4*)(vt + ((((size_t)bb * HH + h) * DKK + dk) * SS + s)) = pk;
            }
        }
    }
}

// ---------------- flash attention v6: v5 + truncation pack (no RNE adds) ----------------
// Truncation bias on P cancels in the softmax ratio (osum computed from the SAME bf16 P);
// residual random error ~0.2% washed out by PV averaging.
__global__ __launch_bounds__(256, 3) void flash(
    const unsigned short* __restrict__ qb, const unsigned short* __restrict__ kb,
    const unsigned short* __restrict__ vt, const unsigned int* __restrict__ mbits,
    unsigned short* __restrict__ ob)
{
    __shared__ unsigned short Ks[2][64*64];   // [parity][perm kpos-row][dk]  (swizzled)
    __shared__ unsigned short Vs[2][64*64];   // [parity][dk-row][kpos]       (swizzled)

    const int bh = blockIdx.y;
    const int bi = bh / HH, h = bh % HH;
    const int tid  = threadIdx.x;
    const int w    = tid >> 6, lane = tid & 63;
    const int quad = lane >> 4, c = lane & 15;
    const int q0w = blockIdx.x * 128 + w * 32;

    bf16x8 qa[2][2];
    #pragma unroll
    for (int mt = 0; mt < 2; mt++) {
        const unsigned short* qbase = qb + (size_t)(bi * SS + q0w + mt * 16 + c) * DD + h * DKK + quad * 8;
        qa[mt][0] = *(const bf16x8*)(qbase);
        qa[mt][1] = *(const bf16x8*)(qbase + 32);
    }

    const int l0 = tid >> 3, sl = tid & 7;
    const int l1 = 32 + l0;
    const int lc = (sl ^ (l0 & 7)) << 3;
    const int kp0 = ((l0 >> 5) << 5) | (((l0 >> 2) & 3) << 3) | (((l0 >> 4) & 1) << 2) | (l0 & 3);
    const int kp1 = ((l1 >> 5) << 5) | (((l1 >> 2) & 3) << 3) | (((l1 >> 4) & 1) << 2) | (l1 & 3);
    const unsigned short* kg0 = kb + ((size_t)bi * SS + kp0) * DD + h * DKK + lc;
    const unsigned short* kg1 = kb + ((size_t)bi * SS + kp1) * DD + h * DKK + lc;
    const unsigned short* vg0 = vt + (((size_t)bi * HH + h) * DKK + l0) * SS + lc;
    const unsigned short* vg1 = vt + (((size_t)bi * HH + h) * DKK + l1) * SS + lc;

    const unsigned int* mrow0 = mbits + (size_t)(bi * SS + q0w + c) * (SS / 32);
    const unsigned int* mrow1 = mrow0 + (size_t)16 * (SS / 32);

    f32x4 o[2][4];
    #pragma unroll
    for (int mt = 0; mt < 2; mt++)
        #pragma unroll
        for (int dt = 0; dt < 4; dt++) o[mt][dt] = (f32x4){0.f, 0.f, 0.f, 0.f};
    f32x4 osum[2] = { (f32x4){0.f,0.f,0.f,0.f}, (f32x4){0.f,0.f,0.f,0.f} };
    const f32x4 ZC = (f32x4){0.f, 0.f, 0.f, 0.f};
    union { unsigned int u[4]; bf16x8 v; } onesu;
    onesu.u[0] = 0x3F803F80u; onesu.u[1] = 0x3F803F80u;
    onesu.u[2] = 0x3F803F80u; onesu.u[3] = 0x3F803F80u;
    const bf16x8 ones = onesu.v;

    const int cswz = c & 7;

    GLDS(kg0, Ks[0] + (size_t)tid * 8);
    GLDS(kg1, Ks[0] + (size_t)(256 + tid) * 8);
    GLDS(vg0, Vs[0] + (size_t)tid * 8);
    GLDS(vg1, Vs[0] + (size_t)(256 + tid) * 8);
    uint2 mw0 = *(const uint2*)(mrow0);
    uint2 mw1 = *(const uint2*)(mrow1);

    for (int t = 0; t < SS / 64; t++) {
        const int k0 = t * 64, par = t & 1;
        __syncthreads();   // drains tile-t staging (issued one full compute phase ago)
        uint2 nw0 = make_uint2(0u, 0u), nw1 = make_uint2(0u, 0u);
        if (t < SS / 64 - 1) {
            const size_t ko = (size_t)(k0 + 64);
            GLDS(kg0 + ko * DD, Ks[par ^ 1] + (size_t)tid * 8);
            GLDS(kg1 + ko * DD, Ks[par ^ 1] + (size_t)(256 + tid) * 8);
            GLDS(vg0 + ko,      Vs[par ^ 1] + (size_t)tid * 8);
            GLDS(vg1 + ko,      Vs[par ^ 1] + (size_t)(256 + tid) * 8);
            nw0 = *(const uint2*)(mrow0 + ((k0 + 64) >> 5));
            nw1 = *(const uint2*)(mrow1 + ((k0 + 64) >> 5));
        }

        const unsigned long long mmq[2] = {
            ((((unsigned long long)mw0.y << 32) | mw0.x) >> (quad * 8)),
            ((((unsigned long long)mw1.y << 32) | mw1.x) >> (quad * 8)) };

        #pragma unroll
        for (int p = 0; p < 2; p++) {
            unsigned int pq[2][4];   // [mt][tt*2 + r2]
            #pragma unroll
            for (int tt = 0; tt < 2; tt++) {
                const unsigned short* kbase = &Ks[par][((2 * p + tt) * 16 + c) << 6];
                const bf16x8 kf0 = *(const bf16x8*)(kbase + ((quad ^ cswz) << 3));
                const bf16x8 kf1 = *(const bf16x8*)(kbase + (((4 + quad) ^ cswz) << 3));
                #pragma unroll
                for (int mt = 0; mt < 2; mt++) {
                    f32x4 st = __builtin_amdgcn_mfma_f32_16x16x32_bf16(kf0, qa[mt][0], ZC, 0, 0, 0);
                    st = __builtin_amdgcn_mfma_f32_16x16x32_bf16(kf1, qa[mt][1], st, 0, 0, 0);
                    const unsigned int mb = (unsigned int)(mmq[mt] >> (p * 32 + tt * 4)) & 15u;
                    #pragma unroll
                    for (int r2 = 0; r2 < 2; r2++) {
                        const float sv0 = (mb & (1u << (r2 * 2)))     ? st[r2 * 2]     : 0.0f;
                        const float sv1 = (mb & (1u << (r2 * 2 + 1))) ? st[r2 * 2 + 1] : 0.0f;
                        const float p0 = __builtin_amdgcn_exp2f(sv0);
                        const float p1 = __builtin_amdgcn_exp2f(sv1);
                        union { float f; unsigned int u; } u0, u1; u0.f = p0; u1.f = p1;
                        pq[mt][tt * 2 + r2] = __builtin_amdgcn_perm(u1.u, u0.u, 0x07060302);  // truncate-pack
                    }
                }
            }
            bf16x8 pbv[2];
            #pragma unroll
            for (int mt = 0; mt < 2; mt++) {
                union { unsigned int u[4]; bf16x8 v; } pb;
                pb.u[0] = pq[mt][0]; pb.u[1] = pq[mt][1];
                pb.u[2] = pq[mt][2]; pb.u[3] = pq[mt][3];
                pbv[mt] = pb.v;
                osum[mt] = __builtin_amdgcn_mfma_f32_16x16x32_bf16(ones, pbv[mt], osum[mt], 0, 0, 0);
            }
            #pragma unroll
            for (int dt = 0; dt < 4; dt++) {
                const bf16x8 vf = *(const bf16x8*)(&Vs[par][((dt * 16 + c) << 6) + ((((p << 2) + quad) ^ cswz) << 3)]);
                #pragma unroll
                for (int mt = 0; mt < 2; mt++)
                    o[mt][dt] = __builtin_amdgcn_mfma_f32_16x16x32_bf16(vf, pbv[mt], o[mt][dt], 0, 0, 0);
            }
        }
        mw0 = nw0; mw1 = nw1;
    }

    #pragma unroll
    for (int mt = 0; mt < 2; mt++) {
        const float rn = __builtin_amdgcn_rcpf(osum[mt][0]);
        unsigned short* op = ob + (size_t)(bi * SS + q0w + mt * 16 + c) * DD + h * DKK + quad * 4;
        #pragma unroll
        for (int dt = 0; dt < 4; dt++) {
            ushort4 pk;
            pk.x = f2bf(o[mt][dt][0] * rn);
            pk.y = f2bf(o[mt][dt][1] * rn);
            pk.z = f2bf(o[mt][dt][2] * rn);
            pk.w = f2bf(o[mt][dt][3] * rn);
            *(ushort4*)(op + dt * 16) = pk;
        }
    }
}

// ---------------- output projection (swapped operands): out = O @ Wo^T + bo ----------------
// Swapped C-layout: col=token, reg=4 consecutive features -> float4 stores + float4 bias.
__global__ __launch_bounds__(256) void gemm_out(
    const unsigned short* __restrict__ A, const unsigned short* __restrict__ W,
    const float* __restrict__ bias, float* __restrict__ out)
{
    __shared__ unsigned short As[128*64];
    __shared__ unsigned short Bs[128*64];
    const int tid  = threadIdx.x;
    const int lane = tid & 63;
    const int w    = tid >> 6;
    const int wm   = w >> 1, wn = w & 1;
    const int quad = lane >> 4, c = lane & 15;
    const int m0 = blockIdx.y * 128, n0 = blockIdx.x * 128;

    f32x4 acc[4][4];   // [tn][tm]
    #pragma unroll
    for (int i = 0; i < 4; i++)
        #pragma unroll
        for (int j = 0; j < 4; j++) acc[i][j] = (f32x4){0.f, 0.f, 0.f, 0.f};

    const unsigned short* Ag[4]; const unsigned short* Wg[4]; int dst[4];
    #pragma unroll
    for (int j = 0; j < 4; j++) {
        const int ch = tid + j * 256;
        const int row = ch >> 3, sl = ch & 7;
        const int lcc = (sl ^ (row & 7)) << 3;
        Ag[j] = A + (size_t)(m0 + row) * DD + lcc;
        Wg[j] = W + (size_t)(n0 + row) * DD + lcc;
        dst[j] = ch * 8;
    }
    const int cswz = c & 7;

    for (int k0 = 0; k0 < DD; k0 += 64) {
        #pragma unroll
        for (int j = 0; j < 4; j++) {
            GLDS(Ag[j] + k0, As + dst[j]);
            GLDS(Wg[j] + k0, Bs + dst[j]);
        }
        __syncthreads();
        #pragma unroll
        for (int kk = 0; kk < 2; kk++) {
            bf16x8 a[4], b[4];
            #pragma unroll
            for (int t = 0; t < 4; t++) {
                const int ra = wm * 64 + t * 16 + c;
                const int rb = wn * 64 + t * 16 + c;
                a[t] = *(const bf16x8*)(As + ra * 64 + (((kk * 4 + quad) ^ cswz) << 3));
                b[t] = *(const bf16x8*)(Bs + rb * 64 + (((kk * 4 + quad) ^ cswz) << 3));
            }
            #pragma unroll
            for (int tn = 0; tn < 4; tn++)
                #pragma unroll
                for (int tm = 0; tm < 4; tm++)
                    acc[tn][tm] = __builtin_amdgcn_mfma_f32_16x16x32_bf16(b[tn], a[tm], acc[tn][tm], 0, 0, 0);
        }
        __syncthreads();
    }

    #pragma unroll
    for (int tn = 0; tn < 4; tn++) {
        const int featbase = n0 + wn * 64 + tn * 16 + quad * 4;
        const float4 bz = *(const float4*)(bias + featbase);
        #pragma unroll
        for (int tm = 0; tm < 4; tm++) {
            const int token = m0 + wm * 64 + tm * 16 + c;
            float4 v;
            v.x = acc[tn][tm][0] + bz.x;
            v.y = acc[tn][tm][1] + bz.y;
            v.z = acc[tn][tm][2] + bz.z;
            v.w = acc[tn][tm][3] + bz.w;
            *(float4*)(out + (size_t)token * DD + featbase) = v;
        }
    }
}

extern "C" void kernel_launch(void* const* d_in, const int* in_sizes, int n_in,
                              void* d_out, int out_size, void* d_ws, size_t ws_size,
                              hipStream_t stream) {
    (void)in_sizes; (void)n_in; (void)out_size; (void)ws_size;
    const float* Q    = (const float*)d_in[0];
    const float* K    = (const float*)d_in[1];
    const float* V    = (const float*)d_in[2];
    const int*   mask = (const int*)d_in[3];
    const float* Wq   = (const float*)d_in[4];
    const float* bq   = (const float*)d_in[5];
    const float* Wk   = (const float*)d_in[6];
    const float* bk   = (const float*)d_in[7];
    const float* Wv   = (const float*)d_in[8];
    const float* bv   = (const float*)d_in[9];
    const float* Wo   = (const float*)d_in[10];
    const float* bo   = (const float*)d_in[11];
    float* out = (float*)d_out;

    char* ws = (char*)d_ws;
    size_t off = 0;
    auto alloc = [&](size_t bytes) { char* p = ws + off; off += (bytes + 255) & ~255ULL; return p; };
    const size_t act = (size_t)MM * DD * 2;
    unsigned short* Qc  = (unsigned short*)alloc(act);
    unsigned short* Kc  = (unsigned short*)alloc(act);
    unsigned short* Vc  = (unsigned short*)alloc(act);
    unsigned short* Wqc = (unsigned short*)alloc((size_t)DD * DD * 2);
    unsigned short* Wkc = (unsigned short*)alloc((size_t)DD * DD * 2);
    unsigned short* Wvc = (unsigned short*)alloc((size_t)DD * DD * 2);
    unsigned short* Woc = (unsigned short*)alloc((size_t)DD * DD * 2);
    unsigned short* qb  = (unsigned short*)alloc(act);
    unsigned short* kb  = (unsigned short*)alloc(act);
    unsigned short* vt  = (unsigned short*)alloc(act);
    unsigned int*  mbits = (unsigned int*)alloc((size_t)BB * SS * (SS / 32) * 4);
    unsigned short* ob = Qc;   // reuse: Qc dead after gemm_qkv

    prep<<<dim3(3 * ABLK + 4 * WBLK + MBLK), 256, 0, stream>>>(
        Q, K, V, Wq, Wk, Wv, Wo, mask, Qc, Kc, Vc, Wqc, Wkc, Wvc, Woc, mbits);
    gemm_qkv<<<dim3(DD / 128, MM / 128, 3), 256, 0, stream>>>(
        Qc, Kc, Vc, Wqc, Wkc, Wvc, bq, bk, bv, qb, kb, vt);
    flash<<<dim3(SS / 128, BB * HH), 256, 0, stream>>>(qb, kb, vt, mbits, ob);
    gemm_out<<<dim3(DD / 128, MM / 128), 256, 0, stream>>>(ob, Woc, bo, out);
}

// Round 8
// 321.473 us; speedup vs baseline: 1.1149x; 1.1149x over previous
//
#include <hip/hip_runtime.h>

#define BB 4
#define SS 2048
#define DD 768
#define HH 12
#define DKK 64
#define MM (BB*SS)   // 8192

typedef __attribute__((ext_vector_type(8))) short bf16x8;
typedef __attribute__((ext_vector_type(4))) float f32x4;

// async 16B global->LDS (m97-verified width)
#define GLDS(g, l) __builtin_amdgcn_global_load_lds( \
    (const __attribute__((address_space(1))) unsigned int*)(g), \
    (__attribute__((address_space(3))) unsigned int*)(l), 16, 0, 0)

__device__ __forceinline__ unsigned short f2bf(float f) {
    union { float f; unsigned int u; } v; v.f = f;
    unsigned int r = v.u + 0x7fffu + ((v.u >> 16) & 1u);   // RNE
    return (unsigned short)(r >> 16);
}

#define EXPSCALE 0.18033688011112042f   // log2(e) / sqrt(DK)

// ---------------- fused prep v2: vectorized cvt + 4x mask bit-pack ----------------
// acts: 2 float4/thread; weights: 2 float4/thread; mask: int4/thread + 4 ballots.
// mbits layout (interleaved): per 256-elem chunk, 8 uint32 = words b0..b3 (64-bit each,
// lo/hi), where bit j of b_i = mask[chunk*256 + 4j + i].
#define ABLK2 (MM*DD/4/512)        // 3072 blocks per activation
#define WBLK2 (DD*DD/4/512)        // 288 blocks per weight
#define MBLK2 (BB*SS*SS/1024)      // 16384 mask blocks
#define SEGW  (3*ABLK2)            // 9216
#define SEGM  (SEGW + 4*WBLK2)     // 10368

__global__ void prep(
    const float* __restrict__ Q, const float* __restrict__ K, const float* __restrict__ V,
    const float* __restrict__ Wq, const float* __restrict__ Wk, const float* __restrict__ Wv,
    const float* __restrict__ Wo, const int* __restrict__ mask,
    unsigned short* __restrict__ Qc, unsigned short* __restrict__ Kc, unsigned short* __restrict__ Vc,
    unsigned short* __restrict__ Wqc, unsigned short* __restrict__ Wkc, unsigned short* __restrict__ Wvc,
    unsigned short* __restrict__ Woc, unsigned int* __restrict__ mbits)
{
    const int bx = blockIdx.x;
    if (bx < SEGW) {
        const int seg = bx / ABLK2;
        const float* s = seg == 0 ? Q : seg == 1 ? K : V;
        unsigned short* d = seg == 0 ? Qc : seg == 1 ? Kc : Vc;
        const int i0 = (bx - seg * ABLK2) * 512 + threadIdx.x;
        #pragma unroll
        for (int j = 0; j < 2; j++) {
            const int i = i0 + j * 256;
            float4 v = ((const float4*)s)[i];
            ushort4 o;
            o.x = f2bf(v.x); o.y = f2bf(v.y); o.z = f2bf(v.z); o.w = f2bf(v.w);
            ((ushort4*)d)[i] = o;
        }
    } else if (bx < SEGM) {
        const int b2 = bx - SEGW;
        const int seg = b2 / WBLK2;
        const float* s = seg == 0 ? Wq : seg == 1 ? Wk : seg == 2 ? Wv : Wo;
        unsigned short* d = seg == 0 ? Wqc : seg == 1 ? Wkc : seg == 2 ? Wvc : Woc;
        const int i0 = (b2 - seg * WBLK2) * 512 + threadIdx.x;
        #pragma unroll
        for (int j = 0; j < 2; j++) {
            const int i = i0 + j * 256;
            float4 v = ((const float4*)s)[i];
            ushort4 o;
            o.x = f2bf(v.x); o.y = f2bf(v.y); o.z = f2bf(v.z); o.w = f2bf(v.w);
            ((ushort4*)d)[i] = o;
        }
    } else {
        const int blk = bx - SEGM;
        const int chunk = blk * 4 + (threadIdx.x >> 6);
        const int l = threadIdx.x & 63;
        const int4 mv = *(const int4*)(mask + (size_t)chunk * 256 + 4 * l);
        const unsigned int nib = (mv.x != 0 ? 1u : 0u) | (mv.y != 0 ? 2u : 0u) |
                                 (mv.z != 0 ? 4u : 0u) | (mv.w != 0 ? 8u : 0u);
        const unsigned long long b0 = __ballot(nib & 1u);
        const unsigned long long b1 = __ballot(nib & 2u);
        const unsigned long long b2 = __ballot(nib & 4u);
        const unsigned long long b3 = __ballot(nib & 8u);
        if (l < 8) {
            const int i = l >> 1;
            const unsigned long long wsel = i == 0 ? b0 : i == 1 ? b1 : i == 2 ? b2 : b3;
            const unsigned int v = (l & 1) ? (unsigned int)(wsel >> 32) : (unsigned int)wsel;
            mbits[(size_t)chunk * 8 + l] = v;
        }
    }
}

// ---------------- QKV projection GEMM, XCD-swizzled 1D grid ----------------
// bid&7 selects XCD-group = M-subset; consecutive same-XCD blocks sweep N over ONE
// A-panel -> A stays L2-local, HBM A-fetch ~1x instead of ~6x.
__global__ __launch_bounds__(256) void gemm_qkv(
    const unsigned short* __restrict__ Qc, const unsigned short* __restrict__ Kc, const unsigned short* __restrict__ Vc,
    const unsigned short* __restrict__ Wq, const unsigned short* __restrict__ Wk, const unsigned short* __restrict__ Wv,
    const float* __restrict__ bq, const float* __restrict__ bk, const float* __restrict__ bv,
    unsigned short* __restrict__ qb, unsigned short* __restrict__ kb, unsigned short* __restrict__ vt)
{
    __shared__ unsigned short As[128*64];
    __shared__ unsigned short Bs[128*64];
    const int bid = blockIdx.x;
    const int xg  = bid & 7;
    const int s   = bid >> 3;          // 0..143
    const int mat = s / 48;
    const int r   = s % 48;
    const int nb  = r % 6;
    const int mb  = (r / 6) * 8 + xg;  // 0..63
    const int m0 = mb * 128, n0 = nb * 128;

    const unsigned short* X = mat == 0 ? Qc : mat == 1 ? Kc : Vc;
    const unsigned short* W = mat == 0 ? Wq : mat == 1 ? Wk : Wv;
    const float* bias        = mat == 0 ? bq : mat == 1 ? bk : bv;

    const int tid  = threadIdx.x;
    const int lane = tid & 63;
    const int w    = tid >> 6;
    const int wm   = w >> 1, wn = w & 1;
    const int quad = lane >> 4, c = lane & 15;

    f32x4 acc[4][4];   // q/k (swapped): acc[tn][tm]; v: acc[tm][tn]
    #pragma unroll
    for (int i = 0; i < 4; i++)
        #pragma unroll
        for (int j = 0; j < 4; j++) acc[i][j] = (f32x4){0.f, 0.f, 0.f, 0.f};

    const unsigned short* Xg[4]; const unsigned short* Wg[4]; int dst[4];
    #pragma unroll
    for (int j = 0; j < 4; j++) {
        const int ch = tid + j * 256;
        const int row = ch >> 3, sl = ch & 7;
        const int lc = (sl ^ (row & 7)) << 3;
        Xg[j] = X + (size_t)(m0 + row) * DD + lc;
        Wg[j] = W + (size_t)(n0 + row) * DD + lc;
        dst[j] = ch * 8;
    }
    const int cswz = c & 7;

    for (int k0 = 0; k0 < DD; k0 += 64) {
        #pragma unroll
        for (int j = 0; j < 4; j++) {
            GLDS(Xg[j] + k0, As + dst[j]);
            GLDS(Wg[j] + k0, Bs + dst[j]);
        }
        __syncthreads();
        #pragma unroll
        for (int kk = 0; kk < 2; kk++) {
            bf16x8 a[4], b[4];
            #pragma unroll
            for (int t = 0; t < 4; t++) {
                const int ra = wm * 64 + t * 16 + c;
                const int rb = wn * 64 + t * 16 + c;
                a[t] = *(const bf16x8*)(As + ra * 64 + (((kk * 4 + quad) ^ cswz) << 3));
                b[t] = *(const bf16x8*)(Bs + rb * 64 + (((kk * 4 + quad) ^ cswz) << 3));
            }
            if (mat < 2) {
                #pragma unroll
                for (int tn = 0; tn < 4; tn++)
                    #pragma unroll
                    for (int tm = 0; tm < 4; tm++)
                        acc[tn][tm] = __builtin_amdgcn_mfma_f32_16x16x32_bf16(b[tn], a[tm], acc[tn][tm], 0, 0, 0);
            } else {
                #pragma unroll
                for (int tm = 0; tm < 4; tm++)
                    #pragma unroll
                    for (int tn = 0; tn < 4; tn++)
                        acc[tm][tn] = __builtin_amdgcn_mfma_f32_16x16x32_bf16(a[tm], b[tn], acc[tm][tn], 0, 0, 0);
            }
        }
        __syncthreads();
    }

    if (mat < 2) {
        unsigned short* out = mat == 0 ? qb : kb;
        const float scale = mat == 0 ? EXPSCALE : 1.0f;
        #pragma unroll
        for (int tn = 0; tn < 4; tn++) {
            const int featbase = n0 + wn * 64 + tn * 16 + quad * 4;
            const float4 bz = *(const float4*)(bias + featbase);
            #pragma unroll
            for (int tm = 0; tm < 4; tm++) {
                const int token = m0 + wm * 64 + tm * 16 + c;
                ushort4 pk;
                pk.x = f2bf((acc[tn][tm][0] + bz.x) * scale);
                pk.y = f2bf((acc[tn][tm][1] + bz.y) * scale);
                pk.z = f2bf((acc[tn][tm][2] + bz.z) * scale);
                pk.w = f2bf((acc[tn][tm][3] + bz.w) * scale);
                *(ushort4*)(out + (size_t)token * DD + featbase) = pk;
            }
        }
    } else {
        #pragma unroll
        for (int tn = 0; tn < 4; tn++) {
            const int col = n0 + wn * 64 + tn * 16 + c;
            const float bz = bias[col];
            const int h = col >> 6, dk = col & 63;
            #pragma unroll
            for (int tm = 0; tm < 4; tm++) {
                const int row = m0 + wm * 64 + tm * 16 + quad * 4;
                const int bb = row >> 11, ss = row & 2047;
                ushort4 pk;
                pk.x = f2bf(acc[tm][tn][0] + bz);
                pk.y = f2bf(acc[tm][tn][1] + bz);
                pk.z = f2bf(acc[tm][tn][2] + bz);
                pk.w = f2bf(acc[tm][tn][3] + bz);
                *(ushort4*)(vt + ((((size_t)bb * HH + h) * DKK + dk) * SS + ss)) = pk;
            }
        }
    }
}

// ---------------- flash attention v8: v7 with the pq clobber bug removed ----------------
// word r of a 256-kpos chunk holds bits of kpos == r (mod 4); for tile t, (p,tt,quad,r):
// bit index in word r = 16*(t&3) + 8p + 2*quad + tt.
__global__ __launch_bounds__(256, 3) void flash(
    const unsigned short* __restrict__ qb, const unsigned short* __restrict__ kb,
    const unsigned short* __restrict__ vt, const unsigned int* __restrict__ mbits,
    unsigned short* __restrict__ ob)
{
    __shared__ unsigned short Ks[2][64*64];   // [parity][perm kpos-row][dk]  (swizzled)
    __shared__ unsigned short Vs[2][64*64];   // [parity][dk-row][kpos]       (swizzled)

    const int bh = blockIdx.y;
    const int bi = bh / HH, h = bh % HH;
    const int tid  = threadIdx.x;
    const int w    = tid >> 6, lane = tid & 63;
    const int quad = lane >> 4, c = lane & 15;
    const int q0w = blockIdx.x * 128 + w * 32;

    bf16x8 qa[2][2];
    #pragma unroll
    for (int mt = 0; mt < 2; mt++) {
        const unsigned short* qbase = qb + (size_t)(bi * SS + q0w + mt * 16 + c) * DD + h * DKK + quad * 8;
        qa[mt][0] = *(const bf16x8*)(qbase);
        qa[mt][1] = *(const bf16x8*)(qbase + 32);
    }

    const int l0 = tid >> 3, sl = tid & 7;
    const int l1 = 32 + l0;
    const int lc = (sl ^ (l0 & 7)) << 3;
    const int kp0 = ((l0 >> 5) << 5) | (((l0 >> 2) & 3) << 3) | (((l0 >> 4) & 1) << 2) | (l0 & 3);
    const int kp1 = ((l1 >> 5) << 5) | (((l1 >> 2) & 3) << 3) | (((l1 >> 4) & 1) << 2) | (l1 & 3);
    const unsigned short* kg0 = kb + ((size_t)bi * SS + kp0) * DD + h * DKK + lc;
    const unsigned short* kg1 = kb + ((size_t)bi * SS + kp1) * DD + h * DKK + lc;
    const unsigned short* vg0 = vt + (((size_t)bi * HH + h) * DKK + l0) * SS + lc;
    const unsigned short* vg1 = vt + (((size_t)bi * HH + h) * DKK + l1) * SS + lc;

    // mbits: 64 words per q-row (interleaved chunk format)
    const unsigned int* mr0 = mbits + (size_t)(bi * SS + q0w + c) * 64;
    const unsigned int* mr1 = mr0 + (size_t)16 * 64;

    f32x4 o[2][4];
    #pragma unroll
    for (int mt = 0; mt < 2; mt++)
        #pragma unroll
        for (int dt = 0; dt < 4; dt++) o[mt][dt] = (f32x4){0.f, 0.f, 0.f, 0.f};
    f32x4 osum[2] = { (f32x4){0.f,0.f,0.f,0.f}, (f32x4){0.f,0.f,0.f,0.f} };
    const f32x4 ZC = (f32x4){0.f, 0.f, 0.f, 0.f};
    union { unsigned int u[4]; bf16x8 v; } onesu;
    onesu.u[0] = 0x3F803F80u; onesu.u[1] = 0x3F803F80u;
    onesu.u[2] = 0x3F803F80u; onesu.u[3] = 0x3F803F80u;
    const bf16x8 ones = onesu.v;

    const int cswz = c & 7;

    GLDS(kg0, Ks[0] + (size_t)tid * 8);
    GLDS(kg1, Ks[0] + (size_t)(256 + tid) * 8);
    GLDS(vg0, Vs[0] + (size_t)tid * 8);
    GLDS(vg1, Vs[0] + (size_t)(256 + tid) * 8);

    uint4 wlo[2], whi[2];

    for (int t = 0; t < SS / 64; t++) {
        const int k0 = t * 64, par = t & 1;
        __syncthreads();   // drains tile-t staging (issued one full compute phase ago)
        if (t < SS / 64 - 1) {
            const size_t ko = (size_t)(k0 + 64);
            GLDS(kg0 + ko * DD, Ks[par ^ 1] + (size_t)tid * 8);
            GLDS(kg1 + ko * DD, Ks[par ^ 1] + (size_t)(256 + tid) * 8);
            GLDS(vg0 + ko,      Vs[par ^ 1] + (size_t)tid * 8);
            GLDS(vg1 + ko,      Vs[par ^ 1] + (size_t)(256 + tid) * 8);
        }

        if ((t & 3) == 0) {
            const int co = (t >> 2) * 8;
            wlo[0] = *(const uint4*)(mr0 + co);
            whi[0] = *(const uint4*)(mr0 + co + 4);
            wlo[1] = *(const uint4*)(mr1 + co);
            whi[1] = *(const uint4*)(mr1 + co + 4);
        }
        const int t16 = (t & 3) * 16;
        unsigned int ww[2][4];
        #pragma unroll
        for (int mt = 0; mt < 2; mt++) {
            ww[mt][0] = (unsigned int)((((unsigned long long)wlo[mt].y << 32) | wlo[mt].x) >> t16);
            ww[mt][1] = (unsigned int)((((unsigned long long)wlo[mt].w << 32) | wlo[mt].z) >> t16);
            ww[mt][2] = (unsigned int)((((unsigned long long)whi[mt].y << 32) | whi[mt].x) >> t16);
            ww[mt][3] = (unsigned int)((((unsigned long long)whi[mt].w << 32) | whi[mt].z) >> t16);
        }

        #pragma unroll
        for (int p = 0; p < 2; p++) {
            unsigned int pq[2][4];   // [mt][tt*2 + r2]
            #pragma unroll
            for (int tt = 0; tt < 2; tt++) {
                const unsigned short* kbase = &Ks[par][((2 * p + tt) * 16 + c) << 6];
                const bf16x8 kf0 = *(const bf16x8*)(kbase + ((quad ^ cswz) << 3));
                const bf16x8 kf1 = *(const bf16x8*)(kbase + (((4 + quad) ^ cswz) << 3));
                const unsigned int sh = (unsigned)(p * 8 + quad * 2 + tt);
                #pragma unroll
                for (int mt = 0; mt < 2; mt++) {
                    f32x4 st = __builtin_amdgcn_mfma_f32_16x16x32_bf16(kf0, qa[mt][0], ZC, 0, 0, 0);
                    st = __builtin_amdgcn_mfma_f32_16x16x32_bf16(kf1, qa[mt][1], st, 0, 0, 0);
                    #pragma unroll
                    for (int r2 = 0; r2 < 2; r2++) {
                        const float sv0 = ((ww[mt][r2 * 2]     >> sh) & 1u) ? st[r2 * 2]     : 0.0f;
                        const float sv1 = ((ww[mt][r2 * 2 + 1] >> sh) & 1u) ? st[r2 * 2 + 1] : 0.0f;
                        const float p0 = __builtin_amdgcn_exp2f(sv0);
                        const float p1 = __builtin_amdgcn_exp2f(sv1);
                        union { float f; unsigned int u; } u0, u1; u0.f = p0; u1.f = p1;
                        pq[mt][tt * 2 + r2] = __builtin_amdgcn_perm(u1.u, u0.u, 0x07060302);  // truncate-pack
                    }
                }
            }
            bf16x8 pbv[2];
            #pragma unroll
            for (int mt = 0; mt < 2; mt++) {
                union { unsigned int u[4]; bf16x8 v; } pb;
                pb.u[0] = pq[mt][0]; pb.u[1] = pq[mt][1];
                pb.u[2] = pq[mt][2]; pb.u[3] = pq[mt][3];
                pbv[mt] = pb.v;
                osum[mt] = __builtin_amdgcn_mfma_f32_16x16x32_bf16(ones, pbv[mt], osum[mt], 0, 0, 0);
            }
            #pragma unroll
            for (int dt = 0; dt < 4; dt++) {
                const bf16x8 vf = *(const bf16x8*)(&Vs[par][((dt * 16 + c) << 6) + ((((p << 2) + quad) ^ cswz) << 3)]);
                #pragma unroll
                for (int mt = 0; mt < 2; mt++)
                    o[mt][dt] = __builtin_amdgcn_mfma_f32_16x16x32_bf16(vf, pbv[mt], o[mt][dt], 0, 0, 0);
            }
        }
    }

    #pragma unroll
    for (int mt = 0; mt < 2; mt++) {
        const float rn = __builtin_amdgcn_rcpf(osum[mt][0]);
        unsigned short* op = ob + (size_t)(bi * SS + q0w + mt * 16 + c) * DD + h * DKK + quad * 4;
        #pragma unroll
        for (int dt = 0; dt < 4; dt++) {
            ushort4 pk;
            pk.x = f2bf(o[mt][dt][0] * rn);
            pk.y = f2bf(o[mt][dt][1] * rn);
            pk.z = f2bf(o[mt][dt][2] * rn);
            pk.w = f2bf(o[mt][dt][3] * rn);
            *(ushort4*)(op + dt * 16) = pk;
        }
    }
}

// ---------------- output projection, XCD-swizzled 1D grid ----------------
__global__ __launch_bounds__(256) void gemm_out(
    const unsigned short* __restrict__ A, const unsigned short* __restrict__ W,
    const float* __restrict__ bias, float* __restrict__ out)
{
    __shared__ unsigned short As[128*64];
    __shared__ unsigned short Bs[128*64];
    const int bid = blockIdx.x;
    const int xg  = bid & 7;
    const int s   = bid >> 3;          // 0..47
    const int nb  = s % 6;
    const int mb  = (s / 6) * 8 + xg;  // 0..63
    const int m0 = mb * 128, n0 = nb * 128;

    const int tid  = threadIdx.x;
    const int lane = tid & 63;
    const int w    = tid >> 6;
    const int wm   = w >> 1, wn = w & 1;
    const int quad = lane >> 4, c = lane & 15;

    f32x4 acc[4][4];   // [tn][tm]
    #pragma unroll
    for (int i = 0; i < 4; i++)
        #pragma unroll
        for (int j = 0; j < 4; j++) acc[i][j] = (f32x4){0.f, 0.f, 0.f, 0.f};

    const unsigned short* Ag[4]; const unsigned short* Wg[4]; int dst[4];
    #pragma unroll
    for (int j = 0; j < 4; j++) {
        const int ch = tid + j * 256;
        const int row = ch >> 3, sl = ch & 7;
        const int lcc = (sl ^ (row & 7)) << 3;
        Ag[j] = A + (size_t)(m0 + row) * DD + lcc;
        Wg[j] = W + (size_t)(n0 + row) * DD + lcc;
        dst[j] = ch * 8;
    }
    const int cswz = c & 7;

    for (int k0 = 0; k0 < DD; k0 += 64) {
        #pragma unroll
        for (int j = 0; j < 4; j++) {
            GLDS(Ag[j] + k0, As + dst[j]);
            GLDS(Wg[j] + k0, Bs + dst[j]);
        }
        __syncthreads();
        #pragma unroll
        for (int kk = 0; kk < 2; kk++) {
            bf16x8 a[4], b[4];
            #pragma unroll
            for (int t = 0; t < 4; t++) {
                const int ra = wm * 64 + t * 16 + c;
                const int rb = wn * 64 + t * 16 + c;
                a[t] = *(const bf16x8*)(As + ra * 64 + (((kk * 4 + quad) ^ cswz) << 3));
                b[t] = *(const bf16x8*)(Bs + rb * 64 + (((kk * 4 + quad) ^ cswz) << 3));
            }
            #pragma unroll
            for (int tn = 0; tn < 4; tn++)
                #pragma unroll
                for (int tm = 0; tm < 4; tm++)
                    acc[tn][tm] = __builtin_amdgcn_mfma_f32_16x16x32_bf16(b[tn], a[tm], acc[tn][tm], 0, 0, 0);
        }
        __syncthreads();
    }

    #pragma unroll
    for (int tn = 0; tn < 4; tn++) {
        const int featbase = n0 + wn * 64 + tn * 16 + quad * 4;
        const float4 bz = *(const float4*)(bias + featbase);
        #pragma unroll
        for (int tm = 0; tm < 4; tm++) {
            const int token = m0 + wm * 64 + tm * 16 + c;
            float4 v;
            v.x = acc[tn][tm][0] + bz.x;
            v.y = acc[tn][tm][1] + bz.y;
            v.z = acc[tn][tm][2] + bz.z;
            v.w = acc[tn][tm][3] + bz.w;
            *(float4*)(out + (size_t)token * DD + featbase) = v;
        }
    }
}

extern "C" void kernel_launch(void* const* d_in, const int* in_sizes, int n_in,
                              void* d_out, int out_size, void* d_ws, size_t ws_size,
                              hipStream_t stream) {
    (void)in_sizes; (void)n_in; (void)out_size; (void)ws_size;
    const float* Q    = (const float*)d_in[0];
    const float* K    = (const float*)d_in[1];
    const float* V    = (const float*)d_in[2];
    const int*   mask = (const int*)d_in[3];
    const float* Wq   = (const float*)d_in[4];
    const float* bq   = (const float*)d_in[5];
    const float* Wk   = (const float*)d_in[6];
    const float* bk   = (const float*)d_in[7];
    const float* Wv   = (const float*)d_in[8];
    const float* bv   = (const float*)d_in[9];
    const float* Wo   = (const float*)d_in[10];
    const float* bo   = (const float*)d_in[11];
    float* out = (float*)d_out;

    char* ws = (char*)d_ws;
    size_t off = 0;
    auto alloc = [&](size_t bytes) { char* p = ws + off; off += (bytes + 255) & ~255ULL; return p; };
    const size_t act = (size_t)MM * DD * 2;
    unsigned short* Qc  = (unsigned short*)alloc(act);
    unsigned short* Kc  = (unsigned short*)alloc(act);
    unsigned short* Vc  = (unsigned short*)alloc(act);
    unsigned short* Wqc = (unsigned short*)alloc((size_t)DD * DD * 2);
    unsigned short* Wkc = (unsigned short*)alloc((size_t)DD * DD * 2);
    unsigned short* Wvc = (unsigned short*)alloc((size_t)DD * DD * 2);
    unsigned short* Woc = (unsigned short*)alloc((size_t)DD * DD * 2);
    unsigned short* qb  = (unsigned short*)alloc(act);
    unsigned short* kb  = (unsigned short*)alloc(act);
    unsigned short* vt  = (unsigned short*)alloc(act);
    unsigned int*  mbits = (unsigned int*)alloc((size_t)BB * SS * (SS / 32) * 4);
    unsigned short* ob = Qc;   // reuse: Qc dead after gemm_qkv

    prep<<<dim3(SEGM + MBLK2), 256, 0, stream>>>(
        Q, K, V, Wq, Wk, Wv, Wo, mask, Qc, Kc, Vc, Wqc, Wkc, Wvc, Woc, mbits);
    gemm_qkv<<<dim3(1152), 256, 0, stream>>>(
        Qc, Kc, Vc, Wqc, Wkc, Wvc, bq, bk, bv, qb, kb, vt);
    flash<<<dim3(SS / 128, BB * HH), 256, 0, stream>>>(qb, kb, vt, mbits, ob);
    gemm_out<<<dim3(384), 256, 0, stream>>>(ob, Woc, bo, out);
}